// Round 5
// baseline (131.692 us; speedup 1.0000x reference)
//
#include <hip/hip_runtime.h>

#define N_FEAT 2048
#define ORDER 8
#define BATCH 8192
#define BLOCK 256
#define WPB 4           // waves per block; one wave owns one batch row

typedef float v4f __attribute__((ext_vector_type(4)));

__device__ __forceinline__ float dot4(v4f a, v4f b) {
    return a.x * b.x + a.y * b.y + a.z * b.z + a.w * b.w;
}

// Prep kernel (1 block): normalize the 8 reflection vectors into ws.
__global__ __launch_bounds__(BLOCK) void prep_kernel(
    const float* __restrict__ v, float* __restrict__ vn) {
    const int tid = threadIdx.x;
    const int lane = tid & 63, wid = tid >> 6;

    v4f a0[ORDER], a1[ORDER];
    #pragma unroll
    for (int i = 0; i < ORDER; ++i) {
        a0[i] = *(const v4f*)(v + (size_t)i * N_FEAT + tid * 4);
        a1[i] = *(const v4f*)(v + (size_t)i * N_FEAT + 1024 + tid * 4);
    }
    float ss[ORDER];
    #pragma unroll
    for (int i = 0; i < ORDER; ++i)
        ss[i] = dot4(a0[i], a0[i]) + dot4(a1[i], a1[i]);
    #pragma unroll
    for (int o = 32; o > 0; o >>= 1)
        #pragma unroll
        for (int i = 0; i < ORDER; ++i) ss[i] += __shfl_down(ss[i], o, 64);

    __shared__ float red[4][ORDER];
    if (lane == 0) {
        #pragma unroll
        for (int i = 0; i < ORDER; ++i) red[wid][i] = ss[i];
    }
    __syncthreads();
    #pragma unroll
    for (int i = 0; i < ORDER; ++i) {
        const float inv = 1.0f / sqrtf(red[0][i] + red[1][i] + red[2][i] + red[3][i]);
        *(v4f*)(vn + (size_t)i * N_FEAT + tid * 4) = a0[i] * inv;
        *(v4f*)(vn + (size_t)i * N_FEAT + 1024 + tid * 4) = a1[i] * inv;
    }
}

// Apply kernel: ONE WAVE PER ROW. Row = 2048 floats = 64 lanes x 8 v4f.
// Per reflection: wave-local dot (shfl_xor butterfly -> every lane holds the
// sum), then axpy. Zero LDS, zero barriers -- waves fully independent.
__global__ __launch_bounds__(BLOCK) void orth_apply_kernel(
    const float* __restrict__ x, const float* __restrict__ vn,
    const float* __restrict__ d, const float* __restrict__ bias,
    float* __restrict__ y) {
    const int tid = threadIdx.x;
    const int lane = tid & 63, wid = tid >> 6;
    const int row = blockIdx.x * WPB + wid;
    const size_t base = (size_t)row * N_FEAT;
    const int col = lane * 4;   // chunk c covers columns c*256 + col .. +3

    v4f z[8];
    #pragma unroll
    for (int c = 0; c < 8; ++c)
        z[c] = *(const v4f*)(x + base + c * 256 + col);

    #pragma unroll
    for (int i = 0; i < ORDER; ++i) {
        const float* vr = vn + (size_t)i * N_FEAT;
        v4f a[8];
        #pragma unroll
        for (int c = 0; c < 8; ++c)
            a[c] = *(const v4f*)(vr + c * 256 + col);

        float p = 0.f;
        #pragma unroll
        for (int c = 0; c < 8; ++c) p += dot4(z[c], a[c]);
        #pragma unroll
        for (int o = 1; o < 64; o <<= 1) p += __shfl_xor(p, o, 64);

        const float s = -2.0f * p;
        #pragma unroll
        for (int c = 0; c < 8; ++c) z[c] += s * a[c];
    }

    #pragma unroll
    for (int c = 0; c < 8; ++c) {
        const v4f dd = *(const v4f*)(d + c * 256 + col);
        const v4f bb = *(const v4f*)(bias + c * 256 + col);
        v4f o = z[c] * dd + bb;
        __builtin_nontemporal_store(o, (v4f*)(y + base + c * 256 + col));
    }
}

extern "C" void kernel_launch(void* const* d_in, const int* in_sizes, int n_in,
                              void* d_out, int out_size, void* d_ws, size_t ws_size,
                              hipStream_t stream) {
    const float* x    = (const float*)d_in[0];  // [8192, 2048]
    const float* v    = (const float*)d_in[1];  // [8, 2048]
    const float* d    = (const float*)d_in[2];  // [2048]
    const float* bias = (const float*)d_in[3];  // [2048]
    float* y  = (float*)d_out;                  // [8192, 2048]
    float* vn = (float*)d_ws;                   // [8, 2048]

    prep_kernel<<<1, BLOCK, 0, stream>>>(v, vn);
    orth_apply_kernel<<<BATCH / WPB, BLOCK, 0, stream>>>(x, vn, d, bias, y);
}